// Round 11
// baseline (473.819 us; speedup 1.0000x reference)
//
#include <hip/hip_runtime.h>
#include <hip/hip_bf16.h>
#include <math.h>

namespace {
constexpr int Bn = 8, Sn = 1024, Hn = 8, DHn = 256, HDn = 2048;
// chunk = 128 rows x 32 k bf16 = 4096 shorts = 8 KB.
// row r, content granule g (k in [g*8,g*8+8), g<4) at shorts r*32 + (g^((r>>1)&3))*8.
constexpr size_t QB0 = 0;
constexpr size_t QB1 = (size_t)20 * 64 * 4096;
constexpr size_t QB2 = QB1 + (size_t)20 * 32 * 4096;
constexpr size_t HB0 = 0;
constexpr size_t HB1 = (size_t)61 * 64 * 4096;
constexpr size_t HB2 = HB1 + (size_t)1 * 32 * 4096;
constexpr size_t OB0 = 0;
constexpr size_t OB1 = (size_t)16 * 64 * 4096;
constexpr size_t OB2 = OB1 + (size_t)8 * 64 * 4096;
}

using bf16x8 = __attribute__((ext_vector_type(8))) short;
using f32x4  = __attribute__((ext_vector_type(4))) float;

__device__ __forceinline__ float bf2f(unsigned short u) {
  unsigned int x = ((unsigned int)u) << 16;
  return __builtin_bit_cast(float, x);
}
__device__ __forceinline__ unsigned short f2bf(float f) {
  unsigned int x = __builtin_bit_cast(unsigned int, f);
  x += 0x7fff + ((x >> 16) & 1);   // RNE
  return (unsigned short)(x >> 16);
}
__device__ __forceinline__ bf16x8 pack8(const float4& u, const float4& v) {
  bf16x8 r;
  r[0] = (short)f2bf(u.x); r[1] = (short)f2bf(u.y); r[2] = (short)f2bf(u.z); r[3] = (short)f2bf(u.w);
  r[4] = (short)f2bf(v.x); r[5] = (short)f2bf(v.y); r[6] = (short)f2bf(v.z); r[7] = (short)f2bf(v.w);
  return r;
}
__device__ __forceinline__ void gload_lds16(const void* g, void* l) {
  __builtin_amdgcn_global_load_lds(
      (const __attribute__((address_space(1))) void*)g,
      (__attribute__((address_space(3))) void*)l, 16, 0, 0);
}

// weight converter body: W [K][N] fp32 -> W^T chunk pair for 64-k slab kb.
__device__ __forceinline__ void convW_body(
    const float* __restrict__ W, unsigned short* __restrict__ dstBase,
    int K, int N, int nb, int kb, float (*S)[132], int t)
{
  const int kl = t >> 5, nq = (t & 31) * 4;
  for (int kk = kl; kk < 64; kk += 8) {
    const float4 v = *(const float4*)(W + (size_t)(kb * 64 + kk) * N + nb * 128 + nq);
    S[kk][nq] = v.x; S[kk][nq + 1] = v.y; S[kk][nq + 2] = v.z; S[kk][nq + 3] = v.w;
  }
  __syncthreads();
  unsigned short* chunk = dstBase + ((size_t)nb * (K >> 5) + kb * 2) * 4096;
#pragma unroll
  for (int j = 0; j < 4; ++j) {
    const int q = t * 4 + j;
    const int r = q >> 3, g = q & 7;
    bf16x8 o;
#pragma unroll
    for (int e = 0; e < 8; ++e) o[e] = (short)f2bf(S[g * 8 + e][r]);
    *(bf16x8*)(chunk + (g >> 2) * 4096 + r * 32 + (((g & 3) ^ ((r >> 1) & 3)) * 8)) = o;
  }
}

// ---------------------------------------------------------------------------
// convAll: all QKV weight + activation conversions in ONE launch.
// ---------------------------------------------------------------------------
__global__ __launch_bounds__(256) void convAll(
    const float* __restrict__ wq0, const float* __restrict__ wk0, const float* __restrict__ wv0,
    const float* __restrict__ wq1, const float* __restrict__ wk1, const float* __restrict__ wv1,
    const float* __restrict__ wq2, const float* __restrict__ wk2, const float* __restrict__ wv2,
    const float* __restrict__ hs0, const float* __restrict__ hs1, const float* __restrict__ hs2,
    unsigned short* __restrict__ qkvT, unsigned short* __restrict__ hsT)
{
  __shared__ float S[64][132];
  const int bid = blockIdx.x;
  const int t = threadIdx.x;

  if (bid < 1280) {
    const float* W; unsigned short* dst; int K, N, nb, kb;
    if (bid < 512)       { W = wq0; dst = qkvT + QB0;                  K = 2048; N = 2048; nb = bid & 15; kb = bid >> 4; }
    else if (bid < 576)  { int r = bid - 512;  W = wk0; dst = qkvT + QB0 + (size_t)16 * 64 * 4096; K = 2048; N = 256; nb = r & 1; kb = r >> 1; }
    else if (bid < 640)  { int r = bid - 576;  W = wv0; dst = qkvT + QB0 + (size_t)18 * 64 * 4096; K = 2048; N = 256; nb = r & 1; kb = r >> 1; }
    else if (bid < 896)  { int r = bid - 640;  W = wq1; dst = qkvT + QB1;                  K = 1024; N = 2048; nb = r & 15; kb = r >> 4; }
    else if (bid < 928)  { int r = bid - 896;  W = wk1; dst = qkvT + QB1 + (size_t)16 * 32 * 4096; K = 1024; N = 256; nb = r & 1; kb = r >> 1; }
    else if (bid < 960)  { int r = bid - 928;  W = wv1; dst = qkvT + QB1 + (size_t)18 * 32 * 4096; K = 1024; N = 256; nb = r & 1; kb = r >> 1; }
    else if (bid < 1216) { int r = bid - 960;  W = wq2; dst = qkvT + QB2;                  K = 1024; N = 2048; nb = r & 15; kb = r >> 4; }
    else if (bid < 1248) { int r = bid - 1216; W = wk2; dst = qkvT + QB2 + (size_t)16 * 32 * 4096; K = 1024; N = 256; nb = r & 1; kb = r >> 1; }
    else                 { int r = bid - 1248; W = wv2; dst = qkvT + QB2 + (size_t)18 * 32 * 4096; K = 1024; N = 256; nb = r & 1; kb = r >> 1; }
    convW_body(W, dst, K, N, nb, kb, S, t);
  } else {
    const float* A; unsigned short* dst; int K, M_total, mb, kb;
    if (bid < 3232)      { int it = bid - 1280; A = hs0; dst = hsT + HB0; K = 2048; M_total = 7744; mb = it >> 5; kb = it & 31; }
    else if (bid < 3248) { int it = bid - 3232; A = hs1; dst = hsT + HB1; K = 1024; M_total = 48;   mb = 0;       kb = it; }
    else                 { int it = bid - 3248; A = hs2; dst = hsT + HB2; K = 1024; M_total = 400;  mb = it >> 4; kb = it & 15; }
    unsigned short* chunk = dst + ((size_t)mb * (K >> 5) + kb * 2) * 4096;
#pragma unroll
    for (int j = 0; j < 4; ++j) {
      const int q = j * 256 + t;
      const int r = q >> 3, g = q & 7;
      int m = mb * 128 + r;
      if (m >= M_total) m = mb * 128;
      const float* src = A + (size_t)m * K + kb * 64 + g * 8;
      const float4 u = *(const float4*)(src);
      const float4 v = *(const float4*)(src + 4);
      *(bf16x8*)(chunk + (g >> 2) * 4096 + r * 32 + (((g & 3) ^ ((r >> 1) & 3)) * 8)) = pack8(u, v);
    }
  }
}

__global__ __launch_bounds__(256) void convWo(
    const float* __restrict__ wo0, const float* __restrict__ wo1, const float* __restrict__ wo2,
    unsigned short* __restrict__ woT)
{
  __shared__ float S[64][132];
  const int bid = blockIdx.x;
  const float* W; unsigned short* dst; int N, nb, kb;
  if (bid < 512)      { W = wo0; dst = woT + OB0; N = 2048; nb = bid & 15; kb = bid >> 4; }
  else if (bid < 768) { int r = bid - 512; W = wo1; dst = woT + OB1; N = 1024; nb = r & 7; kb = r >> 3; }
  else                { int r = bid - 768; W = wo2; dst = woT + OB2; N = 1024; nb = r & 7; kb = r >> 3; }
  convW_body(W, dst, HDn, N, nb, kb, S, threadIdx.x);
}

// ---------------------------------------------------------------------------
// Merged QKV GEMM (unchanged from round 10).
// ---------------------------------------------------------------------------
__global__ __launch_bounds__(256) void gemm_qkv(
    const unsigned short* __restrict__ hsT, const unsigned short* __restrict__ qkvT,
    unsigned short* __restrict__ Qh, unsigned short* __restrict__ Kh,
    unsigned short* __restrict__ Vt)
{
  __shared__ __align__(16) short As[2][4096];
  __shared__ __align__(16) short Bs[2][4096];
  const int tid = threadIdx.x;
  const int w  = tid >> 6, l = tid & 63;
  const int wm = w >> 1,  wn = w & 1;
  const int lc = l & 15,  lg = l >> 4;

  const int bid = blockIdx.x;
  int bx, by, L, K, c_off, M_total;
  const unsigned short *aBase, *wBase;
  if (bid < 1220)      { bx = bid % 20; by = bid / 20; L = 968; K = 2048; c_off = 0;   M_total = 7744; aBase = hsT + HB0; wBase = qkvT + QB0; }
  else if (bid < 1240) { bx = bid - 1220; by = 0;      L = 6;   K = 1024; c_off = 968; M_total = 48;   aBase = hsT + HB1; wBase = qkvT + QB1; }
  else                 { int r = bid - 1240; bx = r % 20; by = r / 20; L = 50; K = 1024; c_off = 974; M_total = 400; aBase = hsT + HB2; wBase = qkvT + QB2; }
  const int kcN = K >> 5;
  const int bm0 = by * 128;

  int region, nbL, cb0;
  if (bx < 16)      { region = 0; nbL = bx;      cb0 = bx * 128; }
  else if (bx < 18) { region = 1; nbL = bx - 16; cb0 = (bx - 16) * 128; }
  else              { region = 2; nbL = bx - 18; cb0 = (bx - 18) * 128; }
  const unsigned short* WTr = wBase +
      (region == 0 ? (size_t)0 : (region == 1 ? (size_t)16 * kcN * 4096
                                              : (size_t)18 * kcN * 4096));
  const char* bChunk0 = (const char*)(WTr + (size_t)nbL * kcN * 4096);
  const char* aChunk0 = (const char*)(aBase + (size_t)by * kcN * 4096);

  f32x4 acc[4][4];
#pragma unroll
  for (int i = 0; i < 4; ++i)
#pragma unroll
    for (int j = 0; j < 4; ++j) acc[i][j] = (f32x4){0.f, 0.f, 0.f, 0.f};

  auto issue = [&](int kc, int nb) {
    const char* sa = aChunk0 + (size_t)kc * 8192;
    const char* sb = bChunk0 + (size_t)kc * 8192;
    char* da = (char*)&As[nb][0];
    char* db = (char*)&Bs[nb][0];
    gload_lds16(sa + tid * 16, da + tid * 16);
    gload_lds16(sa + tid * 16 + 4096, da + tid * 16 + 4096);
    gload_lds16(sb + tid * 16, db + tid * 16);
    gload_lds16(sb + tid * 16 + 4096, db + tid * 16 + 4096);
  };

  issue(0, 0);
  for (int kt = 0; kt < kcN; ++kt) {
    const int cur = kt & 1;
    __builtin_amdgcn_s_barrier();
    if (kt + 1 < kcN) {
      issue(kt + 1, cur ^ 1);
      asm volatile("s_waitcnt vmcnt(4)" ::: "memory");
    } else {
      asm volatile("s_waitcnt vmcnt(0)" ::: "memory");
    }
    __builtin_amdgcn_s_barrier();
    __builtin_amdgcn_sched_barrier(0);
    bf16x8 af[4], bfg[4];
#pragma unroll
    for (int mi = 0; mi < 4; ++mi) {
      const int row = wm * 64 + mi * 16 + lc;
      af[mi] = *(const bf16x8*)((const char*)&As[cur][0] + row * 64 +
                                ((lg ^ ((row >> 1) & 3)) * 16));
    }
#pragma unroll
    for (int ni = 0; ni < 4; ++ni) {
      const int row = wn * 64 + ni * 16 + lc;
      bfg[ni] = *(const bf16x8*)((const char*)&Bs[cur][0] + row * 64 +
                                 ((lg ^ ((row >> 1) & 3)) * 16));
    }
#pragma unroll
    for (int mi = 0; mi < 4; ++mi)
#pragma unroll
      for (int ni = 0; ni < 4; ++ni)
        acc[mi][ni] = __builtin_amdgcn_mfma_f32_16x16x32_bf16(af[mi], bfg[ni], acc[mi][ni], 0, 0, 0);
  }

#pragma unroll
  for (int mi = 0; mi < 4; ++mi) {
    const int gm = bm0 + wm * 64 + mi * 16 + lg * 4;
#pragma unroll
    for (int r = 0; r < 4; ++r) {
      const int m = gm + r;
      if (m < M_total) {
        const int cb = m / L, cs = m - cb * L;
#pragma unroll
        for (int ni = 0; ni < 4; ++ni) {
          const int colL = cb0 + wn * 64 + ni * 16 + lc;
          const unsigned short v = f2bf(acc[mi][ni][r]);
          if (region == 0) {
            const int hh = colL >> 8, dd = colL & 255;
            Qh[(((size_t)cb * Hn + hh) * Sn + c_off + cs) * DHn + dd] = v;
          } else if (region == 1) {
            Kh[((size_t)cb * Sn + c_off + cs) * DHn + colL] = v;
          } else {
            Vt[((size_t)cb * DHn + colL) * Sn + c_off + cs] = v;
          }
        }
      }
    }
  }
}

// ---------------------------------------------------------------------------
// Merged output-projection GEMM (unchanged from round 10).
// ---------------------------------------------------------------------------
__global__ __launch_bounds__(256) void gemm_wo(
    const unsigned short* __restrict__ A, const unsigned short* __restrict__ woT,
    float* __restrict__ C)
{
  __shared__ __align__(16) short As[2][4096];
  __shared__ __align__(16) short Bs[2][4096];
  const int tid = threadIdx.x;
  const int w  = tid >> 6, l = tid & 63;
  const int wm = w >> 1,  wn = w & 1;
  const int lc = l & 15,  lg = l >> 4;

  const int bid = blockIdx.x;
  int bx, by, L, N, a_off, M_total;
  const unsigned short* wb;
  float* Cg;
  if (bid < 976)      { bx = bid & 15; by = bid >> 4; L = 968; N = 2048; a_off = 0;   M_total = 7744; wb = woT + OB0; Cg = C; }
  else if (bid < 984) { bx = bid - 976; by = 0;       L = 6;   N = 1024; a_off = 968; M_total = 48;   wb = woT + OB1; Cg = C + (size_t)7744 * 2048; }
  else                { int r = bid - 984; bx = r & 7; by = r >> 3; L = 50; N = 1024; a_off = 974; M_total = 400; wb = woT + OB2; Cg = C + (size_t)7744 * 2048 + (size_t)48 * 1024; }
  const int bm0 = by * 128;
  const char* chunk0 = (const char*)(wb + (size_t)bx * 64 * 4096);

  const int gcont = (tid & 3) ^ ((tid >> 3) & 3);
  const char* aRow[2];
#pragma unroll
  for (int j = 0; j < 2; ++j) {
    int m = bm0 + (tid >> 2) + j * 64;
    if (m >= M_total) m = 0;
    const int cb = m / L, cs = m - cb * L;
    aRow[j] = (const char*)(A + (size_t)(cb * Sn + a_off + cs) * HDn) + gcont * 16;
  }

  f32x4 acc[4][4];
#pragma unroll
  for (int i = 0; i < 4; ++i)
#pragma unroll
    for (int j = 0; j < 4; ++j) acc[i][j] = (f32x4){0.f, 0.f, 0.f, 0.f};

  auto issue = [&](int kc, int nb) {
    char* da = (char*)&As[nb][0];
    char* db = (char*)&Bs[nb][0];
    gload_lds16(aRow[0] + (size_t)kc * 64, da + tid * 16);
    gload_lds16(aRow[1] + (size_t)kc * 64, da + tid * 16 + 4096);
    const char* sb = chunk0 + (size_t)kc * 8192;
    gload_lds16(sb + tid * 16, db + tid * 16);
    gload_lds16(sb + tid * 16 + 4096, db + tid * 16 + 4096);
  };

  issue(0, 0);
  for (int kt = 0; kt < 64; ++kt) {
    const int cur = kt & 1;
    __builtin_amdgcn_s_barrier();
    if (kt + 1 < 64) {
      issue(kt + 1, cur ^ 1);
      asm volatile("s_waitcnt vmcnt(4)" ::: "memory");
    } else {
      asm volatile("s_waitcnt vmcnt(0)" ::: "memory");
    }
    __builtin_amdgcn_s_barrier();
    __builtin_amdgcn_sched_barrier(0);
    bf16x8 af[4], bfg[4];
#pragma unroll
    for (int mi = 0; mi < 4; ++mi) {
      const int row = wm * 64 + mi * 16 + lc;
      af[mi] = *(const bf16x8*)((const char*)&As[cur][0] + row * 64 +
                                ((lg ^ ((row >> 1) & 3)) * 16));
    }
#pragma unroll
    for (int ni = 0; ni < 4; ++ni) {
      const int row = wn * 64 + ni * 16 + lc;
      bfg[ni] = *(const bf16x8*)((const char*)&Bs[cur][0] + row * 64 +
                                 ((lg ^ ((row >> 1) & 3)) * 16));
    }
#pragma unroll
    for (int mi = 0; mi < 4; ++mi)
#pragma unroll
      for (int ni = 0; ni < 4; ++ni)
        acc[mi][ni] = __builtin_amdgcn_mfma_f32_16x16x32_bf16(af[mi], bfg[ni], acc[mi][ni], 0, 0, 0);
  }

#pragma unroll
  for (int mi = 0; mi < 4; ++mi) {
    const int gm = bm0 + wm * 64 + mi * 16 + lg * 4;
#pragma unroll
    for (int r = 0; r < 4; ++r) {
      const int m = gm + r;
      if (m < M_total) {
        const int cb = m / L, cs = m - cb * L;
#pragma unroll
        for (int ni = 0; ni < 4; ++ni) {
          const int col = bx * 128 + wn * 64 + ni * 16 + lc;
          Cg[(size_t)(cb * L + cs) * N + col] = acc[mi][ni][r];
        }
      }
    }
  }
}

// ---------------------------------------------------------------------------
// RoPE in place on bf16 K [b][s][256].
// ---------------------------------------------------------------------------
__global__ __launch_bounds__(128) void rope_k(
    unsigned short* __restrict__ Kh,
    const int* __restrict__ p0, const int* __restrict__ p1, const int* __restrict__ p2)
{
  const int t = blockIdx.x, b = t >> 10, s = t & 1023;
  int p;
  if (s < 968)      p = p0[b * 968 + s];
  else if (s < 974) p = p1[b * 6 + (s - 968)];
  else              p = p2[b * 50 + (s - 974)];
  const float pf = (float)p;
  const float c0 = -0.07195578415606394f;
  const int d = threadIdx.x;
  const float inv = __expf(c0 * (float)d);
  float cs, sn;
  sincosf(pf * inv, &sn, &cs);
  unsigned short* base = Kh + ((size_t)b * Sn + s) * DHn;
  const float x1 = bf2f(base[d]), x2 = bf2f(base[d + 128]);
  base[d]       = f2bf(x1 * cs - x2 * sn);
  base[d + 128] = f2bf(x2 * cs + x1 * sn);
}

// ---------------------------------------------------------------------------
// MFMA flash attention v5 — 2 heads per wave (MQA flat-M).
// Block = (b, 16 q-rows) x 8 heads, 4 waves; wave w = heads {2w, 2w+1}.
// Every K/V fragment read feeds 2 MFMAs; mask reused across the head pair.
// Staging: per wave 4 K + 4 V + 1 mask(lanes<32) = 9 loads -> vmcnt(9).
// ---------------------------------------------------------------------------
__global__ __launch_bounds__(256) void attn_mfma(
    const unsigned short* __restrict__ Qh, const unsigned short* __restrict__ Kh,
    const unsigned short* __restrict__ Vt, const float* __restrict__ mask,
    const int* __restrict__ p0, const int* __restrict__ p1, const int* __restrict__ p2,
    unsigned short* __restrict__ O)
{
  __shared__ __align__(16) short KsB[2][8192];   // 32 keys x 512B, swizzled
  __shared__ __align__(16) short VsB[2][8192];   // 256 d x 64B, swizzled
  __shared__ __align__(16) float Ms[2][512];     // 16 q-rows x 32 keys
  __shared__ __align__(16) short Pb[4][1024];    // per-wave 2 frags x 512 shorts
  const int tid = threadIdx.x;
  const int w  = tid >> 6;          // wave -> head pair {2w, 2w+1}
  const int l  = tid & 63;
  const int lc = l & 15;
  const int lg = l >> 4;
  const int q0 = blockIdx.x * 16;
  const int b  = blockIdx.z;
  const int srow = q0 + lc;

  const char* KgB = (const char*)(Kh + (size_t)b * Sn * DHn);
  const char* VgB = (const char*)(Vt + (size_t)b * DHn * Sn);

  // stage tile kt: per wave 4 K + 4 V chunks (1 KB) + 512B mask (lanes<32)
  auto stage = [&](int kt, int nb) {
    const char* kg = KgB + (size_t)kt * 16384;
    const char* vg = VgB + (size_t)kt * 64;
#pragma unroll
    for (int j = 0; j < 4; ++j) {
      const int chunk = w * 4 + j;
      const int o = chunk * 1024 + l * 16;
      const int srcK = o ^ (((o >> 9) & 7) << 4);
      gload_lds16(kg + srcK, (char*)&KsB[nb][0] + chunk * 1024);
    }
#pragma unroll
    for (int j = 0; j < 4; ++j) {
      const int chunk = w * 4 + j;
      const int o = chunk * 1024 + l * 16;
      const int x = o ^ (((o >> 7) & 3) << 4);
      gload_lds16(vg + (size_t)(x >> 6) * 2048 + (x & 63),
                  (char*)&VsB[nb][0] + chunk * 1024);
    }
    if (l < 32) {   // mask rows 4w..4w+3 (512 B)
      const float* mg = mask + ((size_t)b * Sn + q0 + 4 * w + (l >> 3)) * Sn
                             + kt * 32 + (l & 7) * 4;
      gload_lds16(mg, (char*)&Ms[nb][0] + w * 512);
    }
  };

  stage(0, 0);   // in flight during Q-load + RoPE

  // ---- Q load + fused RoPE for both heads (shared sincos) ----
  int p;
  if (srow < 968)      p = p0[b * 968 + srow];
  else if (srow < 974) p = p1[b * 6 + (srow - 968)];
  else                 p = p2[b * 50 + (srow - 974)];
  const float pf = (float)p;
  const float c0 = -0.07195578415606394f;

  const unsigned short* qrowA = Qh + (((size_t)b * Hn + 2 * w) * Sn + srow) * DHn;
  const unsigned short* qrowB = Qh + (((size_t)b * Hn + 2 * w + 1) * Sn + srow) * DHn;
  bf16x8 qfA[8], qfB[8];
#pragma unroll
  for (int dt = 0; dt < 8; ++dt) {
    qfA[dt] = *(const bf16x8*)(qrowA + dt * 32 + lg * 8);
    qfB[dt] = *(const bf16x8*)(qrowB + dt * 32 + lg * 8);
  }
#pragma unroll
  for (int dt = 0; dt < 4; ++dt) {
#pragma unroll
    for (int j = 0; j < 8; ++j) {
      const int d = dt * 32 + lg * 8 + j;
      const float inv = __expf(c0 * (float)d);
      float cs, sn;
      sincosf(pf * inv, &sn, &cs);
      {
        const float x1 = bf2f((unsigned short)qfA[dt][j]);
        const float x2 = bf2f((unsigned short)qfA[dt + 4][j]);
        qfA[dt][j]     = (short)f2bf(x1 * cs - x2 * sn);
        qfA[dt + 4][j] = (short)f2bf(x2 * cs + x1 * sn);
      }
      {
        const float x1 = bf2f((unsigned short)qfB[dt][j]);
        const float x2 = bf2f((unsigned short)qfB[dt + 4][j]);
        qfB[dt][j]     = (short)f2bf(x1 * cs - x2 * sn);
        qfB[dt + 4][j] = (short)f2bf(x2 * cs + x1 * sn);
      }
    }
  }

  f32x4 accA[16], accB[16];
#pragma unroll
  for (int i = 0; i < 16; ++i) {
    accA[i] = (f32x4){0.f, 0.f, 0.f, 0.f};
    accB[i] = (f32x4){0.f, 0.f, 0.f, 0.f};
  }
  float lsumA[4] = {0.f, 0.f, 0.f, 0.f};
  float lsumB[4] = {0.f, 0.f, 0.f, 0.f};

  const float C1 = 3.6067376022e-3f;     // 2*(1/800)*log2(e)
  const float RC = -144.26950408889634f; // -100*log2(e)
  const float L2E = 1.4426950408889634f;

  int cur = 0;
  for (int kt = 0; kt < 32; ++kt) {
    if (kt + 1 < 32) {
      stage(kt + 1, cur ^ 1);
      asm volatile("s_waitcnt vmcnt(9)" ::: "memory");   // tile kt complete
    } else {
      asm volatile("s_waitcnt vmcnt(0)" ::: "memory");
    }
    __builtin_amdgcn_s_barrier();
    __builtin_amdgcn_sched_barrier(0);

    const short* Ks = &KsB[cur][0];
    const short* Vs = &VsB[cur][0];
    const float* Mw = &Ms[cur][0];

    // QK^T: each K fragment feeds both heads' MFMA
    f32x4 scA[2], scB[2];
    __builtin_amdgcn_s_setprio(1);
#pragma unroll
    for (int ct = 0; ct < 2; ++ct) {
      f32x4 aA = (f32x4){0.f, 0.f, 0.f, 0.f};
      f32x4 aB = (f32x4){0.f, 0.f, 0.f, 0.f};
      const int row = ct * 16 + lc;
      const int sw = (row & 7) << 4;
#pragma unroll
      for (int dt = 0; dt < 8; ++dt) {
        const int byt = (row * 512 + dt * 64 + lg * 16) ^ sw;
        const bf16x8 kf = *(const bf16x8*)((const char*)Ks + byt);
        aA = __builtin_amdgcn_mfma_f32_16x16x32_bf16(qfA[dt], kf, aA, 0, 0, 0);
        aB = __builtin_amdgcn_mfma_f32_16x16x32_bf16(qfB[dt], kf, aB, 0, 0, 0);
      }
      scA[ct] = aA; scB[ct] = aB;
    }
    __builtin_amdgcn_s_setprio(0);

    // soft-cap + mask + exp -> P for both heads (mask loaded once)
#pragma unroll
    for (int ct = 0; ct < 2; ++ct) {
#pragma unroll
      for (int r = 0; r < 4; ++r) {
        const int row_p = lg * 4 + r;
        const int col = ct * 16 + lc;
        const float mvl = Mw[row_p * 32 + col] * L2E;
        const int gp = (col >> 3) ^ ((row_p >> 1) & 3);
        const int pbyt = row_p * 64 + gp * 16 + (col & 7) * 2;
        {
          const float e2 = __builtin_amdgcn_exp2f(scA[ct][r] * C1);
          const float rr = __builtin_amdgcn_rcpf(e2 + 1.f);
          const float pv = __builtin_amdgcn_exp2f(fmaf(rr, RC, mvl));
          lsumA[r] += pv;
          *((short*)((char*)&Pb[w][0] + pbyt)) = (short)f2bf(pv);
        }
        {
          const float e2 = __builtin_amdgcn_exp2f(scB[ct][r] * C1);
          const float rr = __builtin_amdgcn_rcpf(e2 + 1.f);
          const float pv = __builtin_amdgcn_exp2f(fmaf(rr, RC, mvl));
          lsumB[r] += pv;
          *((short*)((char*)&Pb[w][0] + 1024 + pbyt)) = (short)f2bf(pv);
        }
      }
    }
    const int gp2 = lg ^ ((lc >> 1) & 3);
    const bf16x8 pfA = *(const bf16x8*)((const char*)&Pb[w][0] + lc * 64 + gp2 * 16);
    const bf16x8 pfB = *(const bf16x8*)((const char*)&Pb[w][0] + 1024 + lc * 64 + gp2 * 16);

    // PV: each V fragment feeds both heads' MFMA
    __builtin_amdgcn_s_setprio(1);
#pragma unroll
    for (int nt = 0; nt < 16; ++nt) {
      const int row = nt * 16 + lc;
      const int byt = (row * 64 + lg * 16) ^ (((row >> 1) & 3) << 4);
      const bf16x8 vf = *(const bf16x8*)((const char*)Vs + byt);
      accA[nt] = __builtin_amdgcn_mfma_f32_16x16x32_bf16(pfA, vf, accA[nt], 0, 0, 0);
      accB[nt] = __builtin_amdgcn_mfma_f32_16x16x32_bf16(pfB, vf, accB[nt], 0, 0, 0);
    }
    __builtin_amdgcn_s_setprio(0);

    __builtin_amdgcn_s_barrier();   // buf[cur] fully consumed before restage
    cur ^= 1;
  }

#pragma unroll
  for (int mm = 1; mm < 16; mm <<= 1) {
#pragma unroll
    for (int r = 0; r < 4; ++r) {
      lsumA[r] += __shfl_xor(lsumA[r], mm);
      lsumB[r] += __shfl_xor(lsumB[r], mm);
    }
  }
  float rinvA[4], rinvB[4];
#pragma unroll
  for (int r = 0; r < 4; ++r) {
    rinvA[r] = 1.f / lsumA[r];
    rinvB[r] = 1.f / lsumB[r];
  }

  unsigned short* obA = O + ((size_t)b * Sn + q0 + lg * 4) * HDn + (2 * w) * DHn + lc;
  unsigned short* obB = obA + DHn;
#pragma unroll
  for (int nt = 0; nt < 16; ++nt)
#pragma unroll
    for (int r = 0; r < 4; ++r) {
      obA[(size_t)r * HDn + nt * 16] = f2bf(accA[nt][r] * rinvA[r]);
      obB[(size_t)r * HDn + nt * 16] = f2bf(accB[nt][r] * rinvB[r]);
    }
}

// ---------------------------------------------------------------------------
extern "C" void kernel_launch(void* const* d_in, const int* in_sizes, int n_in,
                              void* d_out, int out_size, void* d_ws, size_t ws_size,
                              hipStream_t stream) {
  (void)in_sizes; (void)n_in; (void)out_size; (void)ws_size;
  const float* hs0  = (const float*)d_in[0];
  const float* hs1  = (const float*)d_in[1];
  const float* hs2  = (const float*)d_in[2];
  const float* mask = (const float*)d_in[3];
  const int*   pos0 = (const int*)d_in[4];
  const int*   pos1 = (const int*)d_in[5];
  const int*   pos2 = (const int*)d_in[6];
  float* out = (float*)d_out;

  unsigned short* Qh = (unsigned short*)d_ws;
  unsigned short* Kh = Qh + (size_t)Bn * Sn * HDn;
  unsigned short* Vt = Kh + (size_t)Bn * Sn * DHn;
  unsigned short* Ob = Vt + (size_t)Bn * Sn * DHn;
  unsigned short* qkvT = Ob;                     // dead until attn
  unsigned short* woT  = Qh;                     // dead after attn
  unsigned short* hsT  = (unsigned short*)out;   // dead once gemm_qkv done

  hipLaunchKernelGGL(convAll, dim3(3312), dim3(256), 0, stream,
                     (const float*)d_in[7],  (const float*)d_in[8],  (const float*)d_in[9],
                     (const float*)d_in[11], (const float*)d_in[12], (const float*)d_in[13],
                     (const float*)d_in[15], (const float*)d_in[16], (const float*)d_in[17],
                     hs0, hs1, hs2, qkvT, hsT);

  hipLaunchKernelGGL(gemm_qkv, dim3(1320), dim3(256), 0, stream,
                     hsT, qkvT, Qh, Kh, Vt);

  hipLaunchKernelGGL(rope_k, dim3(Bn * Sn), dim3(128), 0, stream, Kh, pos0, pos1, pos2);
  hipLaunchKernelGGL(attn_mfma, dim3(Sn / 16, 1, Bn), dim3(256), 0, stream,
                     Qh, Kh, Vt, mask, pos0, pos1, pos2, Ob);

  hipLaunchKernelGGL(convWo, dim3(1024), dim3(256), 0, stream,
                     (const float*)d_in[10], (const float*)d_in[14], (const float*)d_in[18], woT);

  hipLaunchKernelGGL(gemm_wo, dim3(1016), dim3(256), 0, stream, Ob, woT, out);
}

// Round 12
// 425.187 us; speedup vs baseline: 1.1144x; 1.1144x over previous
//
#include <hip/hip_runtime.h>
#include <hip/hip_bf16.h>
#include <math.h>

namespace {
constexpr int Bn = 8, Sn = 1024, Hn = 8, DHn = 256, HDn = 2048;
// chunk = 128 rows x 32 k bf16 = 4096 shorts = 8 KB.
// row r, content granule g (k in [g*8,g*8+8), g<4) at shorts r*32 + (g^((r>>1)&3))*8.
constexpr size_t QB0 = 0;
constexpr size_t QB1 = (size_t)20 * 64 * 4096;
constexpr size_t QB2 = QB1 + (size_t)20 * 32 * 4096;
constexpr size_t HB0 = 0;
constexpr size_t HB1 = (size_t)61 * 64 * 4096;
constexpr size_t HB2 = HB1 + (size_t)1 * 32 * 4096;
constexpr size_t OB0 = 0;
constexpr size_t OB1 = (size_t)16 * 64 * 4096;
constexpr size_t OB2 = OB1 + (size_t)8 * 64 * 4096;
}

using bf16x8 = __attribute__((ext_vector_type(8))) short;
using f32x4  = __attribute__((ext_vector_type(4))) float;

__device__ __forceinline__ float bf2f(unsigned short u) {
  unsigned int x = ((unsigned int)u) << 16;
  return __builtin_bit_cast(float, x);
}
__device__ __forceinline__ unsigned short f2bf(float f) {
  unsigned int x = __builtin_bit_cast(unsigned int, f);
  x += 0x7fff + ((x >> 16) & 1);   // RNE
  return (unsigned short)(x >> 16);
}
__device__ __forceinline__ bf16x8 pack8(const float4& u, const float4& v) {
  bf16x8 r;
  r[0] = (short)f2bf(u.x); r[1] = (short)f2bf(u.y); r[2] = (short)f2bf(u.z); r[3] = (short)f2bf(u.w);
  r[4] = (short)f2bf(v.x); r[5] = (short)f2bf(v.y); r[6] = (short)f2bf(v.z); r[7] = (short)f2bf(v.w);
  return r;
}
__device__ __forceinline__ void gload_lds16(const void* g, void* l) {
  __builtin_amdgcn_global_load_lds(
      (const __attribute__((address_space(1))) void*)g,
      (__attribute__((address_space(3))) void*)l, 16, 0, 0);
}

// weight converter body: W [K][N] fp32 -> W^T chunk pair for 64-k slab kb.
__device__ __forceinline__ void convW_body(
    const float* __restrict__ W, unsigned short* __restrict__ dstBase,
    int K, int N, int nb, int kb, float (*S)[132], int t)
{
  const int kl = t >> 5, nq = (t & 31) * 4;
  for (int kk = kl; kk < 64; kk += 8) {
    const float4 v = *(const float4*)(W + (size_t)(kb * 64 + kk) * N + nb * 128 + nq);
    S[kk][nq] = v.x; S[kk][nq + 1] = v.y; S[kk][nq + 2] = v.z; S[kk][nq + 3] = v.w;
  }
  __syncthreads();
  unsigned short* chunk = dstBase + ((size_t)nb * (K >> 5) + kb * 2) * 4096;
#pragma unroll
  for (int j = 0; j < 4; ++j) {
    const int q = t * 4 + j;
    const int r = q >> 3, g = q & 7;
    bf16x8 o;
#pragma unroll
    for (int e = 0; e < 8; ++e) o[e] = (short)f2bf(S[g * 8 + e][r]);
    *(bf16x8*)(chunk + (g >> 2) * 4096 + r * 32 + (((g & 3) ^ ((r >> 1) & 3)) * 8)) = o;
  }
}

// ---------------------------------------------------------------------------
// convAll: all QKV weight + activation conversions in ONE launch.
// ---------------------------------------------------------------------------
__global__ __launch_bounds__(256) void convAll(
    const float* __restrict__ wq0, const float* __restrict__ wk0, const float* __restrict__ wv0,
    const float* __restrict__ wq1, const float* __restrict__ wk1, const float* __restrict__ wv1,
    const float* __restrict__ wq2, const float* __restrict__ wk2, const float* __restrict__ wv2,
    const float* __restrict__ hs0, const float* __restrict__ hs1, const float* __restrict__ hs2,
    unsigned short* __restrict__ qkvT, unsigned short* __restrict__ hsT)
{
  __shared__ float S[64][132];
  const int bid = blockIdx.x;
  const int t = threadIdx.x;

  if (bid < 1280) {
    const float* W; unsigned short* dst; int K, N, nb, kb;
    if (bid < 512)       { W = wq0; dst = qkvT + QB0;                  K = 2048; N = 2048; nb = bid & 15; kb = bid >> 4; }
    else if (bid < 576)  { int r = bid - 512;  W = wk0; dst = qkvT + QB0 + (size_t)16 * 64 * 4096; K = 2048; N = 256; nb = r & 1; kb = r >> 1; }
    else if (bid < 640)  { int r = bid - 576;  W = wv0; dst = qkvT + QB0 + (size_t)18 * 64 * 4096; K = 2048; N = 256; nb = r & 1; kb = r >> 1; }
    else if (bid < 896)  { int r = bid - 640;  W = wq1; dst = qkvT + QB1;                  K = 1024; N = 2048; nb = r & 15; kb = r >> 4; }
    else if (bid < 928)  { int r = bid - 896;  W = wk1; dst = qkvT + QB1 + (size_t)16 * 32 * 4096; K = 1024; N = 256; nb = r & 1; kb = r >> 1; }
    else if (bid < 960)  { int r = bid - 928;  W = wv1; dst = qkvT + QB1 + (size_t)18 * 32 * 4096; K = 1024; N = 256; nb = r & 1; kb = r >> 1; }
    else if (bid < 1216) { int r = bid - 960;  W = wq2; dst = qkvT + QB2;                  K = 1024; N = 2048; nb = r & 15; kb = r >> 4; }
    else if (bid < 1248) { int r = bid - 1216; W = wk2; dst = qkvT + QB2 + (size_t)16 * 32 * 4096; K = 1024; N = 256; nb = r & 1; kb = r >> 1; }
    else                 { int r = bid - 1248; W = wv2; dst = qkvT + QB2 + (size_t)18 * 32 * 4096; K = 1024; N = 256; nb = r & 1; kb = r >> 1; }
    convW_body(W, dst, K, N, nb, kb, S, t);
  } else {
    const float* A; unsigned short* dst; int K, M_total, mb, kb;
    if (bid < 3232)      { int it = bid - 1280; A = hs0; dst = hsT + HB0; K = 2048; M_total = 7744; mb = it >> 5; kb = it & 31; }
    else if (bid < 3248) { int it = bid - 3232; A = hs1; dst = hsT + HB1; K = 1024; M_total = 48;   mb = 0;       kb = it; }
    else                 { int it = bid - 3248; A = hs2; dst = hsT + HB2; K = 1024; M_total = 400;  mb = it >> 4; kb = it & 15; }
    unsigned short* chunk = dst + ((size_t)mb * (K >> 5) + kb * 2) * 4096;
#pragma unroll
    for (int j = 0; j < 4; ++j) {
      const int q = j * 256 + t;
      const int r = q >> 3, g = q & 7;
      int m = mb * 128 + r;
      if (m >= M_total) m = mb * 128;
      const float* src = A + (size_t)m * K + kb * 64 + g * 8;
      const float4 u = *(const float4*)(src);
      const float4 v = *(const float4*)(src + 4);
      *(bf16x8*)(chunk + (g >> 2) * 4096 + r * 32 + (((g & 3) ^ ((r >> 1) & 3)) * 8)) = pack8(u, v);
    }
  }
}

__global__ __launch_bounds__(256) void convWo(
    const float* __restrict__ wo0, const float* __restrict__ wo1, const float* __restrict__ wo2,
    unsigned short* __restrict__ woT)
{
  __shared__ float S[64][132];
  const int bid = blockIdx.x;
  const float* W; unsigned short* dst; int N, nb, kb;
  if (bid < 512)      { W = wo0; dst = woT + OB0; N = 2048; nb = bid & 15; kb = bid >> 4; }
  else if (bid < 768) { int r = bid - 512; W = wo1; dst = woT + OB1; N = 1024; nb = r & 7; kb = r >> 3; }
  else                { int r = bid - 768; W = wo2; dst = woT + OB2; N = 1024; nb = r & 7; kb = r >> 3; }
  convW_body(W, dst, HDn, N, nb, kb, S, threadIdx.x);
}

// ---------------------------------------------------------------------------
// Merged QKV GEMM (unchanged from round 10).
// ---------------------------------------------------------------------------
__global__ __launch_bounds__(256) void gemm_qkv(
    const unsigned short* __restrict__ hsT, const unsigned short* __restrict__ qkvT,
    unsigned short* __restrict__ Qh, unsigned short* __restrict__ Kh,
    unsigned short* __restrict__ Vt)
{
  __shared__ __align__(16) short As[2][4096];
  __shared__ __align__(16) short Bs[2][4096];
  const int tid = threadIdx.x;
  const int w  = tid >> 6, l = tid & 63;
  const int wm = w >> 1,  wn = w & 1;
  const int lc = l & 15,  lg = l >> 4;

  const int bid = blockIdx.x;
  int bx, by, L, K, c_off, M_total;
  const unsigned short *aBase, *wBase;
  if (bid < 1220)      { bx = bid % 20; by = bid / 20; L = 968; K = 2048; c_off = 0;   M_total = 7744; aBase = hsT + HB0; wBase = qkvT + QB0; }
  else if (bid < 1240) { bx = bid - 1220; by = 0;      L = 6;   K = 1024; c_off = 968; M_total = 48;   aBase = hsT + HB1; wBase = qkvT + QB1; }
  else                 { int r = bid - 1240; bx = r % 20; by = r / 20; L = 50; K = 1024; c_off = 974; M_total = 400; aBase = hsT + HB2; wBase = qkvT + QB2; }
  const int kcN = K >> 5;
  const int bm0 = by * 128;

  int region, nbL, cb0;
  if (bx < 16)      { region = 0; nbL = bx;      cb0 = bx * 128; }
  else if (bx < 18) { region = 1; nbL = bx - 16; cb0 = (bx - 16) * 128; }
  else              { region = 2; nbL = bx - 18; cb0 = (bx - 18) * 128; }
  const unsigned short* WTr = wBase +
      (region == 0 ? (size_t)0 : (region == 1 ? (size_t)16 * kcN * 4096
                                              : (size_t)18 * kcN * 4096));
  const char* bChunk0 = (const char*)(WTr + (size_t)nbL * kcN * 4096);
  const char* aChunk0 = (const char*)(aBase + (size_t)by * kcN * 4096);

  f32x4 acc[4][4];
#pragma unroll
  for (int i = 0; i < 4; ++i)
#pragma unroll
    for (int j = 0; j < 4; ++j) acc[i][j] = (f32x4){0.f, 0.f, 0.f, 0.f};

  auto issue = [&](int kc, int nb) {
    const char* sa = aChunk0 + (size_t)kc * 8192;
    const char* sb = bChunk0 + (size_t)kc * 8192;
    char* da = (char*)&As[nb][0];
    char* db = (char*)&Bs[nb][0];
    gload_lds16(sa + tid * 16, da + tid * 16);
    gload_lds16(sa + tid * 16 + 4096, da + tid * 16 + 4096);
    gload_lds16(sb + tid * 16, db + tid * 16);
    gload_lds16(sb + tid * 16 + 4096, db + tid * 16 + 4096);
  };

  issue(0, 0);
  for (int kt = 0; kt < kcN; ++kt) {
    const int cur = kt & 1;
    __builtin_amdgcn_s_barrier();
    if (kt + 1 < kcN) {
      issue(kt + 1, cur ^ 1);
      asm volatile("s_waitcnt vmcnt(4)" ::: "memory");
    } else {
      asm volatile("s_waitcnt vmcnt(0)" ::: "memory");
    }
    __builtin_amdgcn_s_barrier();
    __builtin_amdgcn_sched_barrier(0);
    bf16x8 af[4], bfg[4];
#pragma unroll
    for (int mi = 0; mi < 4; ++mi) {
      const int row = wm * 64 + mi * 16 + lc;
      af[mi] = *(const bf16x8*)((const char*)&As[cur][0] + row * 64 +
                                ((lg ^ ((row >> 1) & 3)) * 16));
    }
#pragma unroll
    for (int ni = 0; ni < 4; ++ni) {
      const int row = wn * 64 + ni * 16 + lc;
      bfg[ni] = *(const bf16x8*)((const char*)&Bs[cur][0] + row * 64 +
                                 ((lg ^ ((row >> 1) & 3)) * 16));
    }
#pragma unroll
    for (int mi = 0; mi < 4; ++mi)
#pragma unroll
      for (int ni = 0; ni < 4; ++ni)
        acc[mi][ni] = __builtin_amdgcn_mfma_f32_16x16x32_bf16(af[mi], bfg[ni], acc[mi][ni], 0, 0, 0);
  }

#pragma unroll
  for (int mi = 0; mi < 4; ++mi) {
    const int gm = bm0 + wm * 64 + mi * 16 + lg * 4;
#pragma unroll
    for (int r = 0; r < 4; ++r) {
      const int m = gm + r;
      if (m < M_total) {
        const int cb = m / L, cs = m - cb * L;
#pragma unroll
        for (int ni = 0; ni < 4; ++ni) {
          const int colL = cb0 + wn * 64 + ni * 16 + lc;
          const unsigned short v = f2bf(acc[mi][ni][r]);
          if (region == 0) {
            const int hh = colL >> 8, dd = colL & 255;
            Qh[(((size_t)cb * Hn + hh) * Sn + c_off + cs) * DHn + dd] = v;
          } else if (region == 1) {
            Kh[((size_t)cb * Sn + c_off + cs) * DHn + colL] = v;
          } else {
            Vt[((size_t)cb * DHn + colL) * Sn + c_off + cs] = v;
          }
        }
      }
    }
  }
}

// ---------------------------------------------------------------------------
// Merged output-projection GEMM (unchanged from round 10).
// ---------------------------------------------------------------------------
__global__ __launch_bounds__(256) void gemm_wo(
    const unsigned short* __restrict__ A, const unsigned short* __restrict__ woT,
    float* __restrict__ C)
{
  __shared__ __align__(16) short As[2][4096];
  __shared__ __align__(16) short Bs[2][4096];
  const int tid = threadIdx.x;
  const int w  = tid >> 6, l = tid & 63;
  const int wm = w >> 1,  wn = w & 1;
  const int lc = l & 15,  lg = l >> 4;

  const int bid = blockIdx.x;
  int bx, by, L, N, a_off, M_total;
  const unsigned short* wb;
  float* Cg;
  if (bid < 976)      { bx = bid & 15; by = bid >> 4; L = 968; N = 2048; a_off = 0;   M_total = 7744; wb = woT + OB0; Cg = C; }
  else if (bid < 984) { bx = bid - 976; by = 0;       L = 6;   N = 1024; a_off = 968; M_total = 48;   wb = woT + OB1; Cg = C + (size_t)7744 * 2048; }
  else                { int r = bid - 984; bx = r & 7; by = r >> 3; L = 50; N = 1024; a_off = 974; M_total = 400; wb = woT + OB2; Cg = C + (size_t)7744 * 2048 + (size_t)48 * 1024; }
  const int bm0 = by * 128;
  const char* chunk0 = (const char*)(wb + (size_t)bx * 64 * 4096);

  const int gcont = (tid & 3) ^ ((tid >> 3) & 3);
  const char* aRow[2];
#pragma unroll
  for (int j = 0; j < 2; ++j) {
    int m = bm0 + (tid >> 2) + j * 64;
    if (m >= M_total) m = 0;
    const int cb = m / L, cs = m - cb * L;
    aRow[j] = (const char*)(A + (size_t)(cb * Sn + a_off + cs) * HDn) + gcont * 16;
  }

  f32x4 acc[4][4];
#pragma unroll
  for (int i = 0; i < 4; ++i)
#pragma unroll
    for (int j = 0; j < 4; ++j) acc[i][j] = (f32x4){0.f, 0.f, 0.f, 0.f};

  auto issue = [&](int kc, int nb) {
    char* da = (char*)&As[nb][0];
    char* db = (char*)&Bs[nb][0];
    gload_lds16(aRow[0] + (size_t)kc * 64, da + tid * 16);
    gload_lds16(aRow[1] + (size_t)kc * 64, da + tid * 16 + 4096);
    const char* sb = chunk0 + (size_t)kc * 8192;
    gload_lds16(sb + tid * 16, db + tid * 16);
    gload_lds16(sb + tid * 16 + 4096, db + tid * 16 + 4096);
  };

  issue(0, 0);
  for (int kt = 0; kt < 64; ++kt) {
    const int cur = kt & 1;
    __builtin_amdgcn_s_barrier();
    if (kt + 1 < 64) {
      issue(kt + 1, cur ^ 1);
      asm volatile("s_waitcnt vmcnt(4)" ::: "memory");
    } else {
      asm volatile("s_waitcnt vmcnt(0)" ::: "memory");
    }
    __builtin_amdgcn_s_barrier();
    __builtin_amdgcn_sched_barrier(0);
    bf16x8 af[4], bfg[4];
#pragma unroll
    for (int mi = 0; mi < 4; ++mi) {
      const int row = wm * 64 + mi * 16 + lc;
      af[mi] = *(const bf16x8*)((const char*)&As[cur][0] + row * 64 +
                                ((lg ^ ((row >> 1) & 3)) * 16));
    }
#pragma unroll
    for (int ni = 0; ni < 4; ++ni) {
      const int row = wn * 64 + ni * 16 + lc;
      bfg[ni] = *(const bf16x8*)((const char*)&Bs[cur][0] + row * 64 +
                                 ((lg ^ ((row >> 1) & 3)) * 16));
    }
#pragma unroll
    for (int mi = 0; mi < 4; ++mi)
#pragma unroll
      for (int ni = 0; ni < 4; ++ni)
        acc[mi][ni] = __builtin_amdgcn_mfma_f32_16x16x32_bf16(af[mi], bfg[ni], acc[mi][ni], 0, 0, 0);
  }

#pragma unroll
  for (int mi = 0; mi < 4; ++mi) {
    const int gm = bm0 + wm * 64 + mi * 16 + lg * 4;
#pragma unroll
    for (int r = 0; r < 4; ++r) {
      const int m = gm + r;
      if (m < M_total) {
        const int cb = m / L, cs = m - cb * L;
#pragma unroll
        for (int ni = 0; ni < 4; ++ni) {
          const int col = bx * 128 + wn * 64 + ni * 16 + lc;
          Cg[(size_t)(cb * L + cs) * N + col] = acc[mi][ni][r];
        }
      }
    }
  }
}

// ---------------------------------------------------------------------------
// RoPE in place on bf16 K [b][s][256].
// ---------------------------------------------------------------------------
__global__ __launch_bounds__(128) void rope_k(
    unsigned short* __restrict__ Kh,
    const int* __restrict__ p0, const int* __restrict__ p1, const int* __restrict__ p2)
{
  const int t = blockIdx.x, b = t >> 10, s = t & 1023;
  int p;
  if (s < 968)      p = p0[b * 968 + s];
  else if (s < 974) p = p1[b * 6 + (s - 968)];
  else              p = p2[b * 50 + (s - 974)];
  const float pf = (float)p;
  const float c0 = -0.07195578415606394f;
  const int d = threadIdx.x;
  const float inv = __expf(c0 * (float)d);
  float cs, sn;
  sincosf(pf * inv, &sn, &cs);
  unsigned short* base = Kh + ((size_t)b * Sn + s) * DHn;
  const float x1 = bf2f(base[d]), x2 = bf2f(base[d + 128]);
  base[d]       = f2bf(x1 * cs - x2 * sn);
  base[d + 128] = f2bf(x2 * cs + x1 * sn);
}

// ---------------------------------------------------------------------------
// MFMA flash attention v6 = round-10 v4 (head-major, 512 thr, 8 waves) +
// mask quad-buffer prefetched 3 tiles ahead (removes cold-HBM mask fetch
// from the per-kt vmcnt gate). Steady-state: issue KV(kt+1), M(kt+3), wait
// vmcnt(6) -> forces exactly M(kt+1)+KV(kt); tail kt=29/30/31 -> 5/4/0.
// ---------------------------------------------------------------------------
__global__ __launch_bounds__(512) void attn_mfma(
    const unsigned short* __restrict__ Qh, const unsigned short* __restrict__ Kh,
    const unsigned short* __restrict__ Vt, const float* __restrict__ mask,
    const int* __restrict__ p0, const int* __restrict__ p1, const int* __restrict__ p2,
    unsigned short* __restrict__ O)
{
  __shared__ __align__(16) short KsB[2][8192];   // 32 keys x 512B, swizzled
  __shared__ __align__(16) short VsB[2][8192];   // 256 d x 64B, swizzled
  __shared__ __align__(16) float Ms[4][512];     // 16 q-rows x 32 keys, quad-buf
  __shared__ __align__(16) short Pb[8][512];     // per-wave P bounce, swizzled
  const int tid = threadIdx.x;
  const int w  = tid >> 6;          // wave = head
  const int l  = tid & 63;
  const int lc = l & 15;
  const int lg = l >> 4;
  const int q0 = blockIdx.x * 16;
  const int b  = blockIdx.z;
  const int srow = q0 + lc;

  const char* KgB = (const char*)(Kh + (size_t)b * Sn * DHn);
  const char* VgB = (const char*)(Vt + (size_t)b * DHn * Sn);

  // K/V tile stage: per wave 2 K + 2 V chunks = 4 loads
  auto stageKV = [&](int kt, int nb) {
    const char* kg = KgB + (size_t)kt * 16384;
    const char* vg = VgB + (size_t)kt * 64;
#pragma unroll
    for (int j = 0; j < 2; ++j) {
      const int chunk = w * 2 + j;
      const int o = chunk * 1024 + l * 16;
      const int srcK = o ^ (((o >> 9) & 7) << 4);
      gload_lds16(kg + srcK, (char*)&KsB[nb][0] + chunk * 1024);
    }
#pragma unroll
    for (int j = 0; j < 2; ++j) {
      const int chunk = w * 2 + j;
      const int o = chunk * 1024 + l * 16;
      const int x = o ^ (((o >> 7) & 3) << 4);
      gload_lds16(vg + (size_t)(x >> 6) * 2048 + (x & 63),
                  (char*)&VsB[nb][0] + chunk * 1024);
    }
  };
  // mask stage: wave w loads rows 2w..2w+1 (lanes<16), 1 load
  auto stageM = [&](int kt) {
    if (l < 16) {
      const float* mg = mask + ((size_t)b * Sn + q0 + 2 * w + (l >> 3)) * Sn
                             + kt * 32 + (l & 7) * 4;
      gload_lds16(mg, (char*)&Ms[kt & 3][0] + w * 256);
    }
  };

  // prologue: masks 0,1 drained; KV(0) + mask(2) in flight
  stageM(0); stageM(1);
  asm volatile("s_waitcnt vmcnt(0)" ::: "memory");
  stageKV(0, 0); stageM(2);

  // ---- Q load + fused RoPE (head = w) ----
  int p;
  if (srow < 968)      p = p0[b * 968 + srow];
  else if (srow < 974) p = p1[b * 6 + (srow - 968)];
  else                 p = p2[b * 50 + (srow - 974)];
  const float pf = (float)p;
  const float c0 = -0.07195578415606394f;

  const unsigned short* qrow = Qh + (((size_t)b * Hn + w) * Sn + srow) * DHn;
  bf16x8 qf[8];
#pragma unroll
  for (int dt = 0; dt < 8; ++dt)
    qf[dt] = *(const bf16x8*)(qrow + dt * 32 + lg * 8);
#pragma unroll
  for (int dt = 0; dt < 4; ++dt) {
#pragma unroll
    for (int j = 0; j < 8; ++j) {
      const int d = dt * 32 + lg * 8 + j;
      const float inv = __expf(c0 * (float)d);
      float cs, sn;
      sincosf(pf * inv, &sn, &cs);
      const float x1 = bf2f((unsigned short)qf[dt][j]);
      const float x2 = bf2f((unsigned short)qf[dt + 4][j]);
      qf[dt][j]     = (short)f2bf(x1 * cs - x2 * sn);
      qf[dt + 4][j] = (short)f2bf(x2 * cs + x1 * sn);
    }
  }

  f32x4 accO[16];
#pragma unroll
  for (int i = 0; i < 16; ++i) accO[i] = (f32x4){0.f, 0.f, 0.f, 0.f};
  float lsum[4] = {0.f, 0.f, 0.f, 0.f};

  const float C1 = 3.6067376022e-3f;     // 2*(1/800)*log2(e)
  const float RC = -144.26950408889634f; // -100*log2(e)
  const float L2E = 1.4426950408889634f;

  int cur = 0;
  for (int kt = 0; kt < 32; ++kt) {
    if (kt + 1 < 32) stageKV(kt + 1, cur ^ 1);
    if (kt + 3 < 32) stageM(kt + 3);
    // force M(kt+1)+KV(kt) complete; keep KV(kt+1)+M(kt+2,3) in flight
    if (kt <= 28)      { asm volatile("s_waitcnt vmcnt(6)" ::: "memory"); }
    else if (kt == 29) { asm volatile("s_waitcnt vmcnt(5)" ::: "memory"); }
    else if (kt == 30) { asm volatile("s_waitcnt vmcnt(4)" ::: "memory"); }
    else               { asm volatile("s_waitcnt vmcnt(0)" ::: "memory"); }
    __builtin_amdgcn_s_barrier();
    __builtin_amdgcn_sched_barrier(0);

    const short* Ks = &KsB[cur][0];
    const short* Vs = &VsB[cur][0];
    const float* Mw = &Ms[kt & 3][0];

    // QK^T from swizzled K LDS
    f32x4 sc[2];
    __builtin_amdgcn_s_setprio(1);
#pragma unroll
    for (int ct = 0; ct < 2; ++ct) {
      f32x4 acc = (f32x4){0.f, 0.f, 0.f, 0.f};
      const int row = ct * 16 + lc;
      const int sw = (row & 7) << 4;
#pragma unroll
      for (int dt = 0; dt < 8; ++dt) {
        const int byt = (row * 512 + dt * 64 + lg * 16) ^ sw;
        const bf16x8 kf = *(const bf16x8*)((const char*)Ks + byt);
        acc = __builtin_amdgcn_mfma_f32_16x16x32_bf16(qf[dt], kf, acc, 0, 0, 0);
      }
      sc[ct] = acc;
    }
    __builtin_amdgcn_s_setprio(0);

    // soft-cap + mask + exp -> P (bf16) to swizzled wave-private LDS
#pragma unroll
    for (int ct = 0; ct < 2; ++ct) {
#pragma unroll
      for (int r = 0; r < 4; ++r) {
        const int row_p = lg * 4 + r;
        const float mv = Mw[row_p * 32 + ct * 16 + lc];
        const float e2 = __builtin_amdgcn_exp2f(sc[ct][r] * C1);
        const float rr = __builtin_amdgcn_rcpf(e2 + 1.f);
        const float pv = __builtin_amdgcn_exp2f(fmaf(rr, RC, mv * L2E));
        lsum[r] += pv;
        const int col = ct * 16 + lc;
        const int gp = (col >> 3) ^ ((row_p >> 1) & 3);
        *((short*)((char*)&Pb[w][0] + row_p * 64 + gp * 16 + (col & 7) * 2)) =
            (short)f2bf(pv);
      }
    }
    const int gp2 = lg ^ ((lc >> 1) & 3);
    const bf16x8 pfr = *(const bf16x8*)((const char*)&Pb[w][0] + lc * 64 + gp2 * 16);

    // PV from swizzled V LDS
    __builtin_amdgcn_s_setprio(1);
#pragma unroll
    for (int nt = 0; nt < 16; ++nt) {
      const int row = nt * 16 + lc;
      const int byt = (row * 64 + lg * 16) ^ (((row >> 1) & 3) << 4);
      const bf16x8 vf = *(const bf16x8*)((const char*)Vs + byt);
      accO[nt] = __builtin_amdgcn_mfma_f32_16x16x32_bf16(pfr, vf, accO[nt], 0, 0, 0);
    }
    __builtin_amdgcn_s_setprio(0);

    __builtin_amdgcn_s_barrier();   // buf[cur] fully consumed before restage
    cur ^= 1;
  }

#pragma unroll
  for (int mm = 1; mm < 16; mm <<= 1) {
#pragma unroll
    for (int r = 0; r < 4; ++r) lsum[r] += __shfl_xor(lsum[r], mm);
  }
  float rinv[4];
#pragma unroll
  for (int r = 0; r < 4; ++r) rinv[r] = 1.f / lsum[r];

  unsigned short* obase = O + ((size_t)b * Sn + q0 + lg * 4) * HDn + w * DHn + lc;
#pragma unroll
  for (int nt = 0; nt < 16; ++nt)
#pragma unroll
    for (int r = 0; r < 4; ++r)
      obase[(size_t)r * HDn + nt * 16] = f2bf(accO[nt][r] * rinv[r]);
}

// ---------------------------------------------------------------------------
extern "C" void kernel_launch(void* const* d_in, const int* in_sizes, int n_in,
                              void* d_out, int out_size, void* d_ws, size_t ws_size,
                              hipStream_t stream) {
  (void)in_sizes; (void)n_in; (void)out_size; (void)ws_size;
  const float* hs0  = (const float*)d_in[0];
  const float* hs1  = (const float*)d_in[1];
  const float* hs2  = (const float*)d_in[2];
  const float* mask = (const float*)d_in[3];
  const int*   pos0 = (const int*)d_in[4];
  const int*   pos1 = (const int*)d_in[5];
  const int*   pos2 = (const int*)d_in[6];
  float* out = (float*)d_out;

  unsigned short* Qh = (unsigned short*)d_ws;
  unsigned short* Kh = Qh + (size_t)Bn * Sn * HDn;
  unsigned short* Vt = Kh + (size_t)Bn * Sn * DHn;
  unsigned short* Ob = Vt + (size_t)Bn * Sn * DHn;
  unsigned short* qkvT = Ob;                     // dead until attn
  unsigned short* woT  = Qh;                     // dead after attn
  unsigned short* hsT  = (unsigned short*)out;   // dead once gemm_qkv done

  hipLaunchKernelGGL(convAll, dim3(3312), dim3(256), 0, stream,
                     (const float*)d_in[7],  (const float*)d_in[8],  (const float*)d_in[9],
                     (const float*)d_in[11], (const float*)d_in[12], (const float*)d_in[13],
                     (const float*)d_in[15], (const float*)d_in[16], (const float*)d_in[17],
                     hs0, hs1, hs2, qkvT, hsT);

  hipLaunchKernelGGL(gemm_qkv, dim3(1320), dim3(256), 0, stream,
                     hsT, qkvT, Qh, Kh, Vt);

  hipLaunchKernelGGL(rope_k, dim3(Bn * Sn), dim3(128), 0, stream, Kh, pos0, pos1, pos2);
  hipLaunchKernelGGL(attn_mfma, dim3(Sn / 16, 1, Bn), dim3(512), 0, stream,
                     Qh, Kh, Vt, mask, pos0, pos1, pos2, Ob);

  hipLaunchKernelGGL(convWo, dim3(1024), dim3(256), 0, stream,
                     (const float*)d_in[10], (const float*)d_in[14], (const float*)d_in[18], woT);

  hipLaunchKernelGGL(gemm_wo, dim3(1016), dim3(256), 0, stream, Ob, woT, out);
}